// Round 1
// baseline (291.854 us; speedup 1.0000x reference)
//
#include <hip/hip_runtime.h>
#include <stdint.h>

#define DIM 64
#define KC 1024
#define TAU_HALF 5.0e-4f   // flag row if (max1 - max2) < this  <=>  score gap < 1e-3
#define FLAG_CAP 16384

typedef float f32x4 __attribute__((ext_vector_type(4)));
typedef short short8 __attribute__((ext_vector_type(8)));

__device__ __forceinline__ unsigned short bf16_rn(float f) {
  union { float f; uint32_t u; } v; v.f = f;
  uint32_t u = v.u;
  uint32_t r = u + 0x7fffu + ((u >> 16) & 1u);
  return (unsigned short)(r >> 16);
}
__device__ __forceinline__ float bf16_f32(unsigned short h) {
  union { uint32_t u; float f; } v; v.u = ((uint32_t)h) << 16;
  return v.f;
}

// K1: codebook -> bf16 hi/lo split, csqh = -0.5*sum(c^2), zero counters.
__global__ void k1_prep(const float* __restrict__ cb,
                        unsigned short* __restrict__ cb_hi,
                        unsigned short* __restrict__ cb_lo,
                        float* __restrict__ csqh,
                        int* __restrict__ cnt,
                        float* __restrict__ loss_slot) {
  const int k = blockIdx.x, j = threadIdx.x;
  const float c = cb[k * DIM + j];
  const unsigned short hi = bf16_rn(c);
  const float hif = bf16_f32(hi);
  const unsigned short lo = bf16_rn(c - hif);
  cb_hi[k * DIM + j] = hi;
  cb_lo[k * DIM + j] = lo;
  float s = c * c;
  #pragma unroll
  for (int off = 32; off >= 1; off >>= 1) s += __shfl_xor(s, off);
  if (j == 0) csqh[k] = -0.5f * s;
  if (k == 0 && j == 0) { *cnt = 0; *loss_slot = 0.0f; }
}

// K2: 3-split bf16 MFMA argmin. Block = 128 rows, 4 waves (2 row-halves x 2 code-halves).
// acc = z.c - 0.5*c^2  => argmin dist == argmax acc. Track (max1, idx1, max2) per row.
__launch_bounds__(256, 2)
__global__ void k2_argmin(const float* __restrict__ z,
                          const unsigned short* __restrict__ cb_hi,
                          const unsigned short* __restrict__ cb_lo,
                          const float* __restrict__ csqh,
                          float* __restrict__ out_idx,
                          int* __restrict__ cnt,
                          int* __restrict__ flags) {
  __shared__ unsigned short lds_cb[2 * 128 * 64];  // [split][code][k], XOR-swizzled 16B chunks
  __shared__ float lds_csq[KC];
  __shared__ float lds_m1[2][128];
  __shared__ float lds_m2[2][128];
  __shared__ int   lds_i1[2][128];

  const int tid  = threadIdx.x;
  const int lane = tid & 63;
  const int wv   = tid >> 6;
  const int wr   = wv >> 1;   // row half
  const int wc   = wv & 1;    // code half
  const int lg   = lane >> 4; // k-chunk group
  const int lr   = lane & 15;
  const int row0 = blockIdx.x * 128;

  ((f32x4*)lds_csq)[tid] = ((const f32x4*)csqh)[tid];

  // Z fragments: global -> registers, split into bf16 hi/lo. B-operand layout:
  // lane holds z-row (lane&15), 8 contiguous k at (lane>>4)*8 (same k-convention as A).
  short8 zhi[4][2], zlo[4][2];
  #pragma unroll
  for (int rt = 0; rt < 4; ++rt) {
    const int row = row0 + wr * 64 + rt * 16 + lr;
    #pragma unroll
    for (int ks = 0; ks < 2; ++ks) {
      const float* p = z + row * DIM + ks * 32 + lg * 8;
      const f32x4 a = *(const f32x4*)p;
      const f32x4 b = *(const f32x4*)(p + 4);
      short8 h, l;
      #pragma unroll
      for (int e = 0; e < 8; ++e) {
        const float f = (e < 4) ? a[e] : b[e - 4];
        const unsigned short hu = bf16_rn(f);
        const float hf = bf16_f32(hu);
        const unsigned short lu = bf16_rn(f - hf);
        h[e] = (short)hu;
        l[e] = (short)lu;
      }
      zhi[rt][ks] = h;
      zlo[rt][ks] = l;
    }
  }

  float M1[4], M2[4];
  int I1[4];
  #pragma unroll
  for (int rt = 0; rt < 4; ++rt) { M1[rt] = -3.0e38f; M2[rt] = -3.0e38f; I1[rt] = 0; }

  for (int t = 0; t < KC / 128; ++t) {
    __syncthreads();
    // stage codebook tile (hi+lo), swizzled: chunk' = chunk ^ (code&7)
    #pragma unroll
    for (int p = 0; p < 8; ++p) {
      const int linear = p * 256 + tid;
      const int chunk  = linear & 7;
      const int cl     = (linear >> 3) & 127;
      const int split  = linear >> 10;
      const unsigned short* src = (split ? cb_lo : cb_hi) + (t * 128 + cl) * DIM + chunk * 8;
      const uint4 v = *(const uint4*)src;
      const int dst = split * 16384 + cl * 128 + ((chunk * 16) ^ ((cl & 7) << 4));
      *(uint4*)((char*)lds_cb + dst) = v;
    }
    __syncthreads();

    const int iterbase = t * 128 + wc * 64;
    #pragma unroll
    for (int ct = 0; ct < 4; ++ct) {
      const int cbase = iterbase + ct * 16 + lg * 4;          // global code of acc reg 0
      const f32x4 init = *(const f32x4*)&lds_csq[cbase];      // -0.5*c^2 per reg
      short8 cfrag[2][2];
      #pragma unroll
      for (int sp = 0; sp < 2; ++sp) {
        #pragma unroll
        for (int ks = 0; ks < 2; ++ks) {
          const int cl2 = wc * 64 + ct * 16 + lr;
          const int chunk = ks * 4 + lg;
          const int off = sp * 16384 + cl2 * 128 + ((chunk * 16) ^ ((cl2 & 7) << 4));
          cfrag[sp][ks] = *(const short8*)((const char*)lds_cb + off);
        }
      }
      #pragma unroll
      for (int rt = 0; rt < 4; ++rt) {
        f32x4 acc = init;
        acc = __builtin_amdgcn_mfma_f32_16x16x32_bf16(cfrag[0][0], zhi[rt][0], acc, 0, 0, 0);
        acc = __builtin_amdgcn_mfma_f32_16x16x32_bf16(cfrag[0][1], zhi[rt][1], acc, 0, 0, 0);
        acc = __builtin_amdgcn_mfma_f32_16x16x32_bf16(cfrag[0][0], zlo[rt][0], acc, 0, 0, 0);
        acc = __builtin_amdgcn_mfma_f32_16x16x32_bf16(cfrag[0][1], zlo[rt][1], acc, 0, 0, 0);
        acc = __builtin_amdgcn_mfma_f32_16x16x32_bf16(cfrag[1][0], zhi[rt][0], acc, 0, 0, 0);
        acc = __builtin_amdgcn_mfma_f32_16x16x32_bf16(cfrag[1][1], zhi[rt][1], acc, 0, 0, 0);
        #pragma unroll
        for (int j = 0; j < 4; ++j) {
          const float s = acc[j];
          const bool take = s > M1[rt];                 // strict > : first (smallest) idx wins ties
          M2[rt] = fmaxf(M2[rt], fminf(s, M1[rt]));     // loser of (s, old M1) is runner-up cand
          M1[rt] = fmaxf(M1[rt], s);
          I1[rt] = take ? (cbase + j) : I1[rt];
        }
      }
    }
  }

  // cross-lane combine over the 4 k-groups (lanes ^16, ^32), tie-break smaller idx
  #pragma unroll
  for (int rt = 0; rt < 4; ++rt) {
    float m1 = M1[rt], m2 = M2[rt];
    int i1 = I1[rt];
    #pragma unroll
    for (int off = 16; off <= 32; off <<= 1) {
      const float o1 = __shfl_xor(m1, off);
      const float o2 = __shfl_xor(m2, off);
      const int   oi = __shfl_xor(i1, off);
      m2 = fmaxf(fmaxf(m2, o2), fminf(m1, o1));
      const bool take = (o1 > m1) || (o1 == m1 && oi < i1);
      if (take) { m1 = o1; i1 = oi; }
    }
    if (lg == 0) {
      const int r = wr * 64 + rt * 16 + lr;
      lds_m1[wc][r] = m1;
      lds_m2[wc][r] = m2;
      lds_i1[wc][r] = i1;
    }
  }
  __syncthreads();
  if (tid < 128) {
    const float a1 = lds_m1[0][tid], b1 = lds_m1[1][tid];
    const float a2 = lds_m2[0][tid], b2 = lds_m2[1][tid];
    const int   ai = lds_i1[0][tid], bi = lds_i1[1][tid];
    const bool takeB = (b1 > a1) || (b1 == a1 && bi < ai);
    const float m1 = takeB ? b1 : a1;
    const int  idx = takeB ? bi : ai;
    const float m2 = fmaxf(fmaxf(a2, b2), fminf(a1, b1));
    const int row = row0 + tid;
    out_idx[row] = (float)idx;
    if (m1 - m2 < TAU_HALF) {          // ambiguous vs split error -> exact rescue
      const int p = atomicAdd(cnt, 1);
      if (p < FLAG_CAP) flags[p] = row;
    }
  }
}

// K3: exact f32 re-argmin for flagged rows (argmax of z.c - 0.5*c^2, smallest-idx ties)
__global__ void k3_rescue(const float* __restrict__ z,
                          const float* __restrict__ cb,
                          const float* __restrict__ csqh,
                          float* __restrict__ out_idx,
                          const int* __restrict__ cnt,
                          const int* __restrict__ flags) {
  __shared__ float zrow[DIM];
  __shared__ float rv[256];
  __shared__ int   ri[256];
  const int tid = threadIdx.x;
  int n = *cnt;
  if (n > FLAG_CAP) n = FLAG_CAP;
  for (int i = blockIdx.x; i < n; i += gridDim.x) {
    const int row = flags[i];
    __syncthreads();
    if (tid < DIM) zrow[tid] = z[row * DIM + tid];
    __syncthreads();
    float m1 = -3.0e38f;
    int i1 = 0;
    for (int k = tid; k < KC; k += 256) {
      const f32x4* cp = (const f32x4*)(cb + k * DIM);
      float acc = csqh[k];
      #pragma unroll
      for (int j4 = 0; j4 < DIM / 4; ++j4) {
        const f32x4 c4 = cp[j4];
        acc = fmaf(zrow[j4 * 4 + 0], c4[0], acc);
        acc = fmaf(zrow[j4 * 4 + 1], c4[1], acc);
        acc = fmaf(zrow[j4 * 4 + 2], c4[2], acc);
        acc = fmaf(zrow[j4 * 4 + 3], c4[3], acc);
      }
      if (acc > m1) { m1 = acc; i1 = k; }
    }
    rv[tid] = m1; ri[tid] = i1;
    __syncthreads();
    for (int s = 128; s >= 1; s >>= 1) {
      if (tid < s) {
        const float o = rv[tid + s];
        const int  oi = ri[tid + s];
        if (o > rv[tid] || (o == rv[tid] && oi < ri[tid])) { rv[tid] = o; ri[tid] = oi; }
      }
      __syncthreads();
    }
    if (tid == 0) out_idx[row] = (float)ri[0];
    __syncthreads();
  }
}

// K4: gather e = codebook[idx], write z_q (== e forward value), exact f32 loss.
__global__ void k4_finalize(const float* __restrict__ z,
                            const float* __restrict__ cb,
                            const float* __restrict__ out_idx,
                            float* __restrict__ zq,
                            float* __restrict__ loss_slot,
                            float scale) {
  __shared__ float wsum[4];
  const int tid = threadIdx.x;
  const int rl = tid >> 4;
  const int q  = tid & 15;
  const int row = blockIdx.x * 16 + rl;
  const int idx = (int)out_idx[row];
  const f32x4 e  = ((const f32x4*)cb)[idx * 16 + q];
  const f32x4 zz = ((const f32x4*)z)[row * 16 + q];
  ((f32x4*)zq)[row * 16 + q] = e;
  const float d0 = e[0] - zz[0], d1 = e[1] - zz[1], d2 = e[2] - zz[2], d3 = e[3] - zz[3];
  float partial = d0 * d0 + d1 * d1 + d2 * d2 + d3 * d3;
  #pragma unroll
  for (int off = 32; off >= 1; off >>= 1) partial += __shfl_xor(partial, off);
  if ((tid & 63) == 0) wsum[tid >> 6] = partial;
  __syncthreads();
  if (tid == 0) atomicAdd(loss_slot, (wsum[0] + wsum[1] + wsum[2] + wsum[3]) * scale);
}

extern "C" void kernel_launch(void* const* d_in, const int* in_sizes, int n_in,
                              void* d_out, int out_size, void* d_ws, size_t ws_size,
                              hipStream_t stream) {
  const float* z  = (const float*)d_in[0];
  const float* cb = (const float*)d_in[1];
  const int N = in_sizes[0] / DIM;  // 131072

  float* out       = (float*)d_out;
  float* out_idx   = out;                          // [0, N): indices as float
  float* zq        = out + N;                      // [N, N + N*64): z_q
  float* loss_slot = out + N + (size_t)N * DIM;    // last element: vq_loss

  unsigned short* cb_hi = (unsigned short*)d_ws;           // 128 KB
  unsigned short* cb_lo = cb_hi + KC * DIM;                // 128 KB
  float* csqh = (float*)(cb_lo + KC * DIM);                // 4 KB
  int* cnt    = (int*)(csqh + KC);
  int* flags  = cnt + 64;                                  // 64 KB

  const float scale = 1.25f / ((float)N * (float)DIM);     // (1+BETA)/(N*d)

  k1_prep<<<KC, DIM, 0, stream>>>(cb, cb_hi, cb_lo, csqh, cnt, loss_slot);
  k2_argmin<<<N / 128, 256, 0, stream>>>(z, cb_hi, cb_lo, csqh, out_idx, cnt, flags);
  k3_rescue<<<128, 256, 0, stream>>>(z, cb, csqh, out_idx, cnt, flags);
  k4_finalize<<<N / 16, 256, 0, stream>>>(z, cb, out_idx, zq, loss_slot, scale);
}

// Round 4
// 188.714 us; speedup vs baseline: 1.5465x; 1.5465x over previous
//
#include <hip/hip_runtime.h>
#include <stdint.h>

#define DIM 64
#define KC 1024
#define TAU_HALF 5.0e-4f   // flag row if (max1 - max2) < this
#define FLAG_CAP 16384

typedef float f32x4 __attribute__((ext_vector_type(4)));
typedef short short8 __attribute__((ext_vector_type(8)));

__device__ __forceinline__ unsigned short bf16_rn(float f) {
  union { float f; uint32_t u; } v; v.f = f;
  uint32_t u = v.u;
  uint32_t r = u + 0x7fffu + ((u >> 16) & 1u);
  return (unsigned short)(r >> 16);
}
__device__ __forceinline__ float bf16_f32(unsigned short h) {
  union { uint32_t u; float f; } v; v.u = ((uint32_t)h) << 16;
  return v.f;
}

// K1: codebook -> bf16 hi/lo split, csqh = -0.5*sum(c^2), zero counters.
__global__ void k1_prep(const float* __restrict__ cb,
                        unsigned short* __restrict__ cb_hi,
                        unsigned short* __restrict__ cb_lo,
                        float* __restrict__ csqh,
                        int* __restrict__ cnt) {
  const int k = blockIdx.x, j = threadIdx.x;
  const float c = cb[k * DIM + j];
  const unsigned short hi = bf16_rn(c);
  const float hif = bf16_f32(hi);
  const unsigned short lo = bf16_rn(c - hif);
  cb_hi[k * DIM + j] = hi;
  cb_lo[k * DIM + j] = lo;
  float s = c * c;
  #pragma unroll
  for (int off = 32; off >= 1; off >>= 1) s += __shfl_xor(s, off);
  if (j == 0) csqh[k] = -0.5f * s;
  if (k == 0 && j == 0) *cnt = 0;
}

// K2: 3-split bf16 MFMA argmin. Block = 128 rows, 4 waves (2 row-halves x 2 code-halves).
// acc = z.c - 0.5*c^2  => argmin dist == argmax acc. Track (max1, idx1, max2) per row.
__launch_bounds__(256, 2)
__global__ void k2_argmin(const float* __restrict__ z,
                          const unsigned short* __restrict__ cb_hi,
                          const unsigned short* __restrict__ cb_lo,
                          const float* __restrict__ csqh,
                          float* __restrict__ out_idx,
                          int* __restrict__ cnt,
                          int* __restrict__ flags) {
  __shared__ unsigned short lds_cb[2 * 128 * 64];  // [split][code][k], XOR-swizzled 16B chunks
  __shared__ float lds_csq[KC];
  __shared__ float lds_m1[2][128];
  __shared__ float lds_m2[2][128];
  __shared__ int   lds_i1[2][128];

  const int tid  = threadIdx.x;
  const int lane = tid & 63;
  const int wv   = tid >> 6;
  const int wr   = wv >> 1;   // row half
  const int wc   = wv & 1;    // code half
  const int lg   = lane >> 4; // k-chunk group
  const int lr   = lane & 15;
  const int row0 = blockIdx.x * 128;

  ((f32x4*)lds_csq)[tid] = ((const f32x4*)csqh)[tid];

  // Z fragments: global -> registers, split into bf16 hi/lo.
  // hi = truncation (mask low mantissa), lo = RN(f - hi) via v_cvt_pk_bf16_f32.
  short8 zhi[4][2], zlo[4][2];
  #pragma unroll
  for (int rt = 0; rt < 4; ++rt) {
    const int row = row0 + wr * 64 + rt * 16 + lr;
    #pragma unroll
    for (int ks = 0; ks < 2; ++ks) {
      const float* p = z + row * DIM + ks * 32 + lg * 8;
      const f32x4 va = *(const f32x4*)p;
      const f32x4 vb = *(const f32x4*)(p + 4);
      union { uint32_t w[4]; short8 s8; } H, L;
      #pragma unroll
      for (int pr = 0; pr < 4; ++pr) {
        const float f0 = (pr < 2) ? va[2 * pr]     : vb[2 * pr - 4];
        const float f1 = (pr < 2) ? va[2 * pr + 1] : vb[2 * pr - 3];
        const uint32_t u0 = __float_as_uint(f0);
        const uint32_t u1 = __float_as_uint(f1);
        H.w[pr] = __builtin_amdgcn_perm(u1, u0, 0x07060302u);  // {u1.hi16, u0.hi16}
        const float l0 = f0 - __uint_as_float(u0 & 0xffff0000u);
        const float l1 = f1 - __uint_as_float(u1 & 0xffff0000u);
        uint32_t lw;
        asm("v_cvt_pk_bf16_f32 %0, %1, %2" : "=v"(lw) : "v"(l0), "v"(l1));
        L.w[pr] = lw;
      }
      zhi[rt][ks] = H.s8;
      zlo[rt][ks] = L.s8;
    }
  }

  float M1[4], M2[4];
  int I1[4];
  #pragma unroll
  for (int rt = 0; rt < 4; ++rt) { M1[rt] = -3.0e38f; M2[rt] = -3.0e38f; I1[rt] = 0; }

  for (int t = 0; t < KC / 128; ++t) {
    __syncthreads();
    // stage codebook tile (hi+lo), swizzled: chunk' = chunk ^ (code&7)
    #pragma unroll
    for (int p = 0; p < 8; ++p) {
      const int linear = p * 256 + tid;
      const int chunk  = linear & 7;
      const int cl     = (linear >> 3) & 127;
      const int split  = linear >> 10;
      const unsigned short* src = (split ? cb_lo : cb_hi) + (t * 128 + cl) * DIM + chunk * 8;
      const uint4 v = *(const uint4*)src;
      const int dst = split * 16384 + cl * 128 + ((chunk * 16) ^ ((cl & 7) << 4));
      *(uint4*)((char*)lds_cb + dst) = v;
    }
    __syncthreads();

    const int iterbase = t * 128 + wc * 64;
    #pragma unroll
    for (int ct = 0; ct < 4; ++ct) {
      const int cbase = iterbase + ct * 16 + lg * 4;          // global code of acc reg 0
      const f32x4 init = *(const f32x4*)&lds_csq[cbase];      // -0.5*c^2 per reg
      short8 cfrag[2][2];
      #pragma unroll
      for (int sp = 0; sp < 2; ++sp) {
        #pragma unroll
        for (int ks = 0; ks < 2; ++ks) {
          const int cl2 = wc * 64 + ct * 16 + lr;
          const int chunk = ks * 4 + lg;
          const int off = sp * 16384 + cl2 * 128 + ((chunk * 16) ^ ((cl2 & 7) << 4));
          cfrag[sp][ks] = *(const short8*)((const char*)lds_cb + off);
        }
      }
      #pragma unroll
      for (int rt = 0; rt < 4; ++rt) {
        f32x4 acc = init;
        acc = __builtin_amdgcn_mfma_f32_16x16x32_bf16(cfrag[0][0], zhi[rt][0], acc, 0, 0, 0);
        acc = __builtin_amdgcn_mfma_f32_16x16x32_bf16(cfrag[0][1], zhi[rt][1], acc, 0, 0, 0);
        acc = __builtin_amdgcn_mfma_f32_16x16x32_bf16(cfrag[0][0], zlo[rt][0], acc, 0, 0, 0);
        acc = __builtin_amdgcn_mfma_f32_16x16x32_bf16(cfrag[0][1], zlo[rt][1], acc, 0, 0, 0);
        acc = __builtin_amdgcn_mfma_f32_16x16x32_bf16(cfrag[1][0], zhi[rt][0], acc, 0, 0, 0);
        acc = __builtin_amdgcn_mfma_f32_16x16x32_bf16(cfrag[1][1], zhi[rt][1], acc, 0, 0, 0);
        #pragma unroll
        for (int j = 0; j < 4; ++j) {
          const float s = acc[j];
          // invariant M1>=M2 holds => median(s, M1, M2) is the new runner-up
          M2[rt] = __builtin_amdgcn_fmed3f(s, M1[rt], M2[rt]);
          const bool take = s > M1[rt];                 // strict > : smallest idx wins ties
          M1[rt] = fmaxf(s, M1[rt]);
          I1[rt] = take ? (cbase + j) : I1[rt];
        }
      }
    }
  }

  // cross-lane combine over the 4 k-groups (lanes ^16, ^32), tie-break smaller idx
  #pragma unroll
  for (int rt = 0; rt < 4; ++rt) {
    float m1 = M1[rt], m2 = M2[rt];
    int i1 = I1[rt];
    #pragma unroll
    for (int off = 16; off <= 32; off <<= 1) {
      const float o1 = __shfl_xor(m1, off);
      const float o2 = __shfl_xor(m2, off);
      const int   oi = __shfl_xor(i1, off);
      m2 = fmaxf(fmaxf(m2, o2), fminf(m1, o1));
      const bool take = (o1 > m1) || (o1 == m1 && oi < i1);
      if (take) { m1 = o1; i1 = oi; }
    }
    if (lg == 0) {
      const int r = wr * 64 + rt * 16 + lr;
      lds_m1[wc][r] = m1;
      lds_m2[wc][r] = m2;
      lds_i1[wc][r] = i1;
    }
  }
  __syncthreads();
  if (tid < 128) {
    const float a1 = lds_m1[0][tid], b1 = lds_m1[1][tid];
    const float a2 = lds_m2[0][tid], b2 = lds_m2[1][tid];
    const int   ai = lds_i1[0][tid], bi = lds_i1[1][tid];
    const bool takeB = (b1 > a1) || (b1 == a1 && bi < ai);
    const float m1 = takeB ? b1 : a1;
    const int  idx = takeB ? bi : ai;
    const float m2 = fmaxf(fmaxf(a2, b2), fminf(a1, b1));
    const int row = row0 + tid;
    out_idx[row] = (float)idx;
    if (m1 - m2 < TAU_HALF) {          // ambiguous vs split error -> exact rescue
      const int p = atomicAdd(cnt, 1);
      if (p < FLAG_CAP) flags[p] = row;
    }
  }
}

// K3: exact f32 re-argmin for flagged rows (argmax of z.c - 0.5*c^2, smallest-idx ties)
__global__ void k3_rescue(const float* __restrict__ z,
                          const float* __restrict__ cb,
                          const float* __restrict__ csqh,
                          float* __restrict__ out_idx,
                          const int* __restrict__ cnt,
                          const int* __restrict__ flags) {
  __shared__ float zrow[DIM];
  __shared__ float rv[256];
  __shared__ int   ri[256];
  const int tid = threadIdx.x;
  int n = *cnt;
  if (n > FLAG_CAP) n = FLAG_CAP;
  for (int i = blockIdx.x; i < n; i += gridDim.x) {
    const int row = flags[i];
    __syncthreads();
    if (tid < DIM) zrow[tid] = z[row * DIM + tid];
    __syncthreads();
    float m1 = -3.0e38f;
    int i1 = 0;
    for (int k = tid; k < KC; k += 256) {
      const f32x4* cp = (const f32x4*)(cb + k * DIM);
      float acc = csqh[k];
      #pragma unroll
      for (int j4 = 0; j4 < DIM / 4; ++j4) {
        const f32x4 c4 = cp[j4];
        acc = fmaf(zrow[j4 * 4 + 0], c4[0], acc);
        acc = fmaf(zrow[j4 * 4 + 1], c4[1], acc);
        acc = fmaf(zrow[j4 * 4 + 2], c4[2], acc);
        acc = fmaf(zrow[j4 * 4 + 3], c4[3], acc);
      }
      if (acc > m1) { m1 = acc; i1 = k; }
    }
    rv[tid] = m1; ri[tid] = i1;
    __syncthreads();
    for (int s = 128; s >= 1; s >>= 1) {
      if (tid < s) {
        const float o = rv[tid + s];
        const int  oi = ri[tid + s];
        if (o > rv[tid] || (o == rv[tid] && oi < ri[tid])) { rv[tid] = o; ri[tid] = oi; }
      }
      __syncthreads();
    }
    if (tid == 0) out_idx[row] = (float)ri[0];
    __syncthreads();
  }
}

// K4: gather e = codebook[idx], write z_q, per-block loss partial -> ws (NO atomics).
__global__ void k4_finalize(const float* __restrict__ z,
                            const float* __restrict__ cb,
                            const float* __restrict__ out_idx,
                            float* __restrict__ zq,
                            float* __restrict__ partials) {
  __shared__ float wsum[4];
  const int tid = threadIdx.x;
  const int rl = tid >> 4;
  const int q  = tid & 15;
  const int row = blockIdx.x * 16 + rl;
  const int idx = (int)out_idx[row];
  const f32x4 e  = ((const f32x4*)cb)[idx * 16 + q];
  const f32x4 zz = ((const f32x4*)z)[row * 16 + q];
  ((f32x4*)zq)[row * 16 + q] = e;
  const float d0 = e[0] - zz[0], d1 = e[1] - zz[1], d2 = e[2] - zz[2], d3 = e[3] - zz[3];
  float partial = d0 * d0 + d1 * d1 + d2 * d2 + d3 * d3;
  #pragma unroll
  for (int off = 32; off >= 1; off >>= 1) partial += __shfl_xor(partial, off);
  if ((tid & 63) == 0) wsum[tid >> 6] = partial;
  __syncthreads();
  if (tid == 0) partials[blockIdx.x] = wsum[0] + wsum[1] + wsum[2] + wsum[3];
}

// K5: reduce 8192 partials -> loss (single block, deterministic tree)
__global__ void k5_reduce(const float* __restrict__ partials,
                          float* __restrict__ loss_slot,
                          float scale, int nb) {
  __shared__ float wsum[4];
  const int tid = threadIdx.x;
  float s = 0.0f;
  for (int i = tid; i < nb / 4; i += 256) {
    const f32x4 v = ((const f32x4*)partials)[i];
    s += (v[0] + v[1]) + (v[2] + v[3]);
  }
  #pragma unroll
  for (int off = 32; off >= 1; off >>= 1) s += __shfl_xor(s, off);
  if ((tid & 63) == 0) wsum[tid >> 6] = s;
  __syncthreads();
  if (tid == 0) *loss_slot = (wsum[0] + wsum[1] + wsum[2] + wsum[3]) * scale;
}

extern "C" void kernel_launch(void* const* d_in, const int* in_sizes, int n_in,
                              void* d_out, int out_size, void* d_ws, size_t ws_size,
                              hipStream_t stream) {
  const float* z  = (const float*)d_in[0];
  const float* cb = (const float*)d_in[1];
  const int N = in_sizes[0] / DIM;  // 131072

  float* out       = (float*)d_out;
  float* out_idx   = out;                          // [0, N): indices as float
  float* zq        = out + N;                      // [N, N + N*64): z_q
  float* loss_slot = out + N + (size_t)N * DIM;    // last element: vq_loss

  unsigned short* cb_hi = (unsigned short*)d_ws;           // 128 KB
  unsigned short* cb_lo = cb_hi + KC * DIM;                // 128 KB
  float* csqh = (float*)(cb_lo + KC * DIM);                // 4 KB
  int* cnt    = (int*)(csqh + KC);
  int* flags  = cnt + 64;                                  // 64 KB
  float* partials = (float*)(flags + FLAG_CAP);            // 32 KB

  const int nb4 = N / 16;                                  // 8192 k4 blocks
  const float scale = 1.25f / ((float)N * (float)DIM);     // (1+BETA)/(N*d)

  k1_prep<<<KC, DIM, 0, stream>>>(cb, cb_hi, cb_lo, csqh, cnt);
  k2_argmin<<<N / 128, 256, 0, stream>>>(z, cb_hi, cb_lo, csqh, out_idx, cnt, flags);
  k3_rescue<<<128, 256, 0, stream>>>(z, cb, csqh, out_idx, cnt, flags);
  k4_finalize<<<nb4, 256, 0, stream>>>(z, cb, out_idx, zq, partials);
  k5_reduce<<<1, 256, 0, stream>>>(partials, loss_slot, scale, nb4);
}

// Round 6
// 185.464 us; speedup vs baseline: 1.5736x; 1.0175x over previous
//
#include <hip/hip_runtime.h>
#include <stdint.h>

#define DIM 64
#define KC 1024
#define TILE 64
#define NT (KC / TILE)
#define TAU_HALF 5.0e-4f   // flag row if (max1 - max2) < this
#define FLAG_CAP 16384

typedef float f32x4 __attribute__((ext_vector_type(4)));
typedef short short8 __attribute__((ext_vector_type(8)));

__device__ __forceinline__ unsigned short bf16_rn(float f) {
  union { float f; uint32_t u; } v; v.f = f;
  uint32_t u = v.u;
  uint32_t r = u + 0x7fffu + ((u >> 16) & 1u);
  return (unsigned short)(r >> 16);
}
__device__ __forceinline__ float bf16_f32(unsigned short h) {
  union { uint32_t u; float f; } v; v.u = ((uint32_t)h) << 16;
  return v.f;
}
__device__ __forceinline__ void gll16(const void* g, void* l) {
  __builtin_amdgcn_global_load_lds(
      (const __attribute__((address_space(1))) void*)g,
      (__attribute__((address_space(3))) void*)l, 16, 0, 0);
}

// K1: codebook -> bf16 hi/lo split, csqh = -0.5*sum(c^2), zero counters.
__global__ void k1_prep(const float* __restrict__ cb,
                        unsigned short* __restrict__ cb_hi,
                        unsigned short* __restrict__ cb_lo,
                        float* __restrict__ csqh,
                        int* __restrict__ cnt) {
  const int k = blockIdx.x, j = threadIdx.x;
  const float c = cb[k * DIM + j];
  const unsigned short hi = bf16_rn(c);
  const float hif = bf16_f32(hi);
  const unsigned short lo = bf16_rn(c - hif);
  cb_hi[k * DIM + j] = hi;
  cb_lo[k * DIM + j] = lo;
  float s = c * c;
  #pragma unroll
  for (int off = 32; off >= 1; off >>= 1) s += __shfl_xor(s, off);
  if (j == 0) csqh[k] = -0.5f * s;
  if (k == 0 && j == 0) *cnt = 0;
}

// K2: 3-split bf16 MFMA argmin + fused loss partials (||z-e||^2 = ||z||^2 - 2*m1).
// Block = 128 rows, 4 waves (2 row-halves x 2 code-halves). 64-code double-buffered
// tiles staged via global_load_lds with pre-swizzled global source (linear LDS dest).
__launch_bounds__(256, 4)
__global__ void k2_argmin(const float* __restrict__ z,
                          const unsigned short* __restrict__ cb_hi,
                          const unsigned short* __restrict__ cb_lo,
                          const float* __restrict__ csqh,
                          float* __restrict__ out_idx,
                          int* __restrict__ cnt,
                          int* __restrict__ flags,
                          float* __restrict__ partials) {
  __shared__ unsigned short lds_cb[2 * 8192];  // 2 x 16KB tile buffers (hi 8KB + lo 8KB each)
  __shared__ float lds_csq[KC];                // 4KB

  const int tid  = threadIdx.x;
  const int lane = tid & 63;
  const int wv   = tid >> 6;
  const int wr   = wv >> 1;   // row half
  const int wc   = wv & 1;    // code half
  const int lg   = lane >> 4; // k-chunk group
  const int lr   = lane & 15;
  const int row0 = blockIdx.x * 128;

  // staging source pointers (pre-swizzled): call p covers split=p>>1;
  // lane -> code cl = (p&1)*32 + wv*8 + (lane>>3), chunk slot ch = lane&7,
  // whose CONTENT must be global chunk ch ^ (cl&7)  (XOR involution).
  const unsigned short* gsrc[4];
  #pragma unroll
  for (int p = 0; p < 4; ++p) {
    const int cl = (p & 1) * 32 + wv * 8 + (lane >> 3);
    const int ch = (lane & 7) ^ (cl & 7);
    gsrc[p] = ((p >> 1) ? cb_lo : cb_hi) + cl * DIM + ch * 8;
  }

#define STAGE(tt, bs)                                                         \
  {                                                                           \
    const int _toff = (tt) * (TILE * DIM);                                    \
    _Pragma("unroll")                                                         \
    for (int p = 0; p < 4; ++p) {                                             \
      gll16(gsrc[p] + _toff,                                                  \
            (char*)lds_cb + (bs) * 16384 + (p * 256 + wv * 64) * 16);         \
    }                                                                         \
  }

  STAGE(0, 0);                                   // prefetch tile 0
  ((f32x4*)lds_csq)[tid] = ((const f32x4*)csqh)[tid];

  // Z fragments: global -> registers, bf16 hi/lo split; also ||z||^2 partials.
  short8 zhi[4][2], zlo[4][2];
  float zsq[4];
  #pragma unroll
  for (int rt = 0; rt < 4; ++rt) {
    const int row = row0 + wr * 64 + rt * 16 + lr;
    float sq = 0.0f;
    #pragma unroll
    for (int ks = 0; ks < 2; ++ks) {
      const float* p = z + row * DIM + ks * 32 + lg * 8;
      const f32x4 va = *(const f32x4*)p;
      const f32x4 vb = *(const f32x4*)(p + 4);
      sq = fmaf(va[0], va[0], sq); sq = fmaf(va[1], va[1], sq);
      sq = fmaf(va[2], va[2], sq); sq = fmaf(va[3], va[3], sq);
      sq = fmaf(vb[0], vb[0], sq); sq = fmaf(vb[1], vb[1], sq);
      sq = fmaf(vb[2], vb[2], sq); sq = fmaf(vb[3], vb[3], sq);
      union { uint32_t w[4]; short8 s8; } H, L;
      #pragma unroll
      for (int pr = 0; pr < 4; ++pr) {
        const float f0 = (pr < 2) ? va[2 * pr]     : vb[2 * pr - 4];
        const float f1 = (pr < 2) ? va[2 * pr + 1] : vb[2 * pr - 3];
        const uint32_t u0 = __float_as_uint(f0);
        const uint32_t u1 = __float_as_uint(f1);
        H.w[pr] = __builtin_amdgcn_perm(u1, u0, 0x07060302u);  // {u1.hi16, u0.hi16}
        const float l0 = f0 - __uint_as_float(u0 & 0xffff0000u);
        const float l1 = f1 - __uint_as_float(u1 & 0xffff0000u);
        uint32_t lw;
        asm("v_cvt_pk_bf16_f32 %0, %1, %2" : "=v"(lw) : "v"(l0), "v"(l1));
        L.w[pr] = lw;
      }
      zhi[rt][ks] = H.s8;
      zlo[rt][ks] = L.s8;
    }
    zsq[rt] = sq;
  }

  float M1[4], M2[4];
  int I1[4];
  #pragma unroll
  for (int rt = 0; rt < 4; ++rt) { M1[rt] = -3.0e38f; M2[rt] = -3.0e38f; I1[rt] = 0; }

  __syncthreads();                               // tile 0 + csq landed

  for (int t = 0; t < NT; ++t) {
    if (t < NT - 1) STAGE(t + 1, (t + 1) & 1);   // prefetch next tile (flies under compute)
    const char* bufb = (const char*)lds_cb + (t & 1) * 16384;
    #pragma unroll
    for (int ct = 0; ct < 2; ++ct) {
      const int cbase = t * TILE + wc * 32 + ct * 16 + lg * 4;
      const f32x4 init = *(const f32x4*)&lds_csq[cbase];     // -0.5*c^2 per acc reg
      const int cl2 = wc * 32 + ct * 16 + lr;
      short8 cf[2][2];
      #pragma unroll
      for (int sp = 0; sp < 2; ++sp) {
        #pragma unroll
        for (int ks = 0; ks < 2; ++ks) {
          const int off = sp * 8192 + cl2 * 128 + (((ks * 4 + lg) ^ (cl2 & 7)) * 16);
          cf[sp][ks] = *(const short8*)(bufb + off);
        }
      }
      #pragma unroll
      for (int rt = 0; rt < 4; ++rt) {
        f32x4 acc = init;
        acc = __builtin_amdgcn_mfma_f32_16x16x32_bf16(cf[0][0], zhi[rt][0], acc, 0, 0, 0);
        acc = __builtin_amdgcn_mfma_f32_16x16x32_bf16(cf[0][1], zhi[rt][1], acc, 0, 0, 0);
        acc = __builtin_amdgcn_mfma_f32_16x16x32_bf16(cf[0][0], zlo[rt][0], acc, 0, 0, 0);
        acc = __builtin_amdgcn_mfma_f32_16x16x32_bf16(cf[0][1], zlo[rt][1], acc, 0, 0, 0);
        acc = __builtin_amdgcn_mfma_f32_16x16x32_bf16(cf[1][0], zhi[rt][0], acc, 0, 0, 0);
        acc = __builtin_amdgcn_mfma_f32_16x16x32_bf16(cf[1][1], zhi[rt][1], acc, 0, 0, 0);
        #pragma unroll
        for (int j = 0; j < 4; ++j) {
          const float s = acc[j];
          M2[rt] = __builtin_amdgcn_fmed3f(s, M1[rt], M2[rt]);  // invariant M1>=M2
          const bool take = s > M1[rt];
          M1[rt] = fmaxf(s, M1[rt]);
          I1[rt] = take ? (cbase + j) : I1[rt];
        }
      }
    }
    __syncthreads();   // drains vmcnt (next tile staged) + protects buffer swap
  }

  // ---- epilogue: reuse lds_cb as scratch (all compute done past last barrier) ----
  float* S  = (float*)lds_cb;       // [0..255]   m1[wc][128]
  float* S2 = S + 256;              // [256..511] m2[wc][128]
  int*   SI = (int*)(S + 512);      // [512..767] i1[wc][128]
  float* ZS = (float*)(SI + 256);   // [768..895] zsq[128]
  float* CT = ZS + 128;             // [896..1023] contribs

  #pragma unroll
  for (int rt = 0; rt < 4; ++rt) {
    float m1 = M1[rt], m2 = M2[rt];
    int i1 = I1[rt];
    #pragma unroll
    for (int off = 16; off <= 32; off <<= 1) {
      const float o1 = __shfl_xor(m1, off);
      const float o2 = __shfl_xor(m2, off);
      const int   oi = __shfl_xor(i1, off);
      m2 = fmaxf(fmaxf(m2, o2), fminf(m1, o1));
      const bool take = (o1 > m1) || (o1 == m1 && oi < i1);
      if (take) { m1 = o1; i1 = oi; }
    }
    float zq = zsq[rt];
    zq += __shfl_xor(zq, 16);
    zq += __shfl_xor(zq, 32);
    if (lg == 0) {
      const int r = wr * 64 + rt * 16 + lr;
      S[wc * 128 + r]  = m1;
      S2[wc * 128 + r] = m2;
      SI[wc * 128 + r] = i1;
      if (wc == 0) ZS[r] = zq;
    }
  }
  __syncthreads();
  if (tid < 128) {
    const float a1 = S[tid],  b1 = S[128 + tid];
    const float a2 = S2[tid], b2 = S2[128 + tid];
    const int   ai = SI[tid], bi = SI[128 + tid];
    const bool takeB = (b1 > a1) || (b1 == a1 && bi < ai);
    const float m1 = takeB ? b1 : a1;
    const int  idx = takeB ? bi : ai;
    const float m2 = fmaxf(fmaxf(a2, b2), fminf(a1, b1));
    const int row = row0 + tid;
    out_idx[row] = (float)idx;
    CT[tid] = ZS[tid] - 2.0f * m1;               // ||z-e||^2 for this row
    if (m1 - m2 < TAU_HALF) {                    // ambiguous -> exact rescue
      const int p = atomicAdd(cnt, 1);
      if (p < FLAG_CAP) flags[p] = row;
    }
  }
  __syncthreads();
  if (tid < 64) {
    float c = CT[tid] + CT[tid + 64];
    #pragma unroll
    for (int off = 32; off >= 1; off >>= 1) c += __shfl_xor(c, off);
    if (tid == 0) partials[blockIdx.x] = c;
  }
#undef STAGE
}

// K3: exact f32 re-argmin for flagged rows, one wave per row (no block barriers).
// Per-code math identical to the previously-passing version (csqh init + seq fma).
__global__ void k3_rescue(const float* __restrict__ z,
                          const float* __restrict__ cb,
                          const float* __restrict__ csqh,
                          float* __restrict__ out_idx,
                          const int* __restrict__ cnt,
                          const int* __restrict__ flags) {
  int n = *cnt;
  if (n > FLAG_CAP) n = FLAG_CAP;
  const int lane = threadIdx.x & 63;
  const int w = blockIdx.x * 4 + (threadIdx.x >> 6);
  for (int i = w; i < n; i += gridDim.x * 4) {
    const int row = flags[i];
    const f32x4* zr4 = (const f32x4*)(z + (size_t)row * DIM);
    float m1 = -3.0e38f;
    int i1 = 0;
    for (int kk = 0; kk < 16; ++kk) {
      const int k = lane * 16 + kk;
      const f32x4* cp = (const f32x4*)(cb + (size_t)k * DIM);
      float acc = csqh[k];
      #pragma unroll
      for (int j4 = 0; j4 < DIM / 4; ++j4) {
        const f32x4 c4 = cp[j4];
        const f32x4 z4 = zr4[j4];
        acc = fmaf(z4[0], c4[0], acc);
        acc = fmaf(z4[1], c4[1], acc);
        acc = fmaf(z4[2], c4[2], acc);
        acc = fmaf(z4[3], c4[3], acc);
      }
      if (acc > m1) { m1 = acc; i1 = k; }
    }
    #pragma unroll
    for (int off = 32; off >= 1; off >>= 1) {
      const float o1 = __shfl_xor(m1, off);
      const int   oi = __shfl_xor(i1, off);
      if (o1 > m1 || (o1 == m1 && oi < i1)) { m1 = o1; i1 = oi; }
    }
    if (lane == 0) out_idx[row] = (float)i1;
  }
}

// K4: pure gather + write z_q (loss already folded into k2).
__global__ void k4_scatter(const float* __restrict__ cb,
                           const float* __restrict__ out_idx,
                           float* __restrict__ zq) {
  const int gid = blockIdx.x * 256 + threadIdx.x;
  const int row = gid >> 2;
  const int q0  = (gid & 3) * 4;
  const int idx = (int)out_idx[row];
  const f32x4* src = (const f32x4*)(cb + (size_t)idx * DIM) + q0;
  f32x4* dst = (f32x4*)(zq + (size_t)row * DIM) + q0;
  dst[0] = src[0]; dst[1] = src[1]; dst[2] = src[2]; dst[3] = src[3];
}

// K5: reduce 1024 block partials -> loss (single block, deterministic tree)
__global__ void k5_reduce(const float* __restrict__ partials,
                          float* __restrict__ loss_slot,
                          float scale, int nb) {
  __shared__ float wsum[4];
  const int tid = threadIdx.x;
  float s = 0.0f;
  for (int i = tid; i < nb / 4; i += 256) {
    const f32x4 v = ((const f32x4*)partials)[i];
    s += (v[0] + v[1]) + (v[2] + v[3]);
  }
  #pragma unroll
  for (int off = 32; off >= 1; off >>= 1) s += __shfl_xor(s, off);
  if ((tid & 63) == 0) wsum[tid >> 6] = s;
  __syncthreads();
  if (tid == 0) *loss_slot = (wsum[0] + wsum[1] + wsum[2] + wsum[3]) * scale;
}

extern "C" void kernel_launch(void* const* d_in, const int* in_sizes, int n_in,
                              void* d_out, int out_size, void* d_ws, size_t ws_size,
                              hipStream_t stream) {
  const float* z  = (const float*)d_in[0];
  const float* cb = (const float*)d_in[1];
  const int N = in_sizes[0] / DIM;  // 131072

  float* out       = (float*)d_out;
  float* out_idx   = out;                          // [0, N): indices as float
  float* zq        = out + N;                      // [N, N + N*64): z_q
  float* loss_slot = out + N + (size_t)N * DIM;    // last element: vq_loss

  unsigned short* cb_hi = (unsigned short*)d_ws;           // 128 KB
  unsigned short* cb_lo = cb_hi + KC * DIM;                // 128 KB
  float* csqh = (float*)(cb_lo + KC * DIM);                // 4 KB
  int* cnt    = (int*)(csqh + KC);
  int* flags  = cnt + 64;                                  // 64 KB
  float* partials = (float*)(flags + FLAG_CAP);            // 4 KB (1024 blocks)

  const int nb2 = N / 128;                                 // 1024 k2 blocks
  const float scale = 1.25f / ((float)N * (float)DIM);     // (1+BETA)/(N*d)

  k1_prep<<<KC, DIM, 0, stream>>>(cb, cb_hi, cb_lo, csqh, cnt);
  k2_argmin<<<nb2, 256, 0, stream>>>(z, cb_hi, cb_lo, csqh, out_idx, cnt, flags, partials);
  k3_rescue<<<256, 256, 0, stream>>>(z, cb, csqh, out_idx, cnt, flags);
  k4_scatter<<<N / 64, 256, 0, stream>>>(cb, out_idx, zq);
  k5_reduce<<<1, 256, 0, stream>>>(partials, loss_slot, scale, nb2);
}